// Round 6
// baseline (949.326 us; speedup 1.0000x reference)
//
#include <hip/hip_runtime.h>
#include <cstdint>

// GridEncoder forward (torch-ngp semantics), MI355X.
// B = 1048576 points, D=3, L=16 levels, C=2, H=16, per_level_scale=2.0,
// log2_hashmap_size=19, align_corners=False.
//
// Level metadata:
//   res(l)   = 16 << l, scale(l) = res - 1
//   dense levels 0,1,2: offsets 0, 4920, 40864, base = res+1,
//     idx = cx + cy*base + cz*base^2
//   hashed levels 3..15: size 2^19, idx = hash & 0x7FFFF,
//     offset(l) = l*524288 - 1257368
//   primes (1, 2654435761, 805459861)
//
// R9 theory of record:
//  * Gather currency = L2->L1 RETURN BYTES, not requests: R3/R5/R7 all
//    ~64 B/pt -> 395-438 us; R8's 16 B paired loads = 128 B/pt -> 600 us
//    (1.5x). 8 B diverged dwordx2 per corner is optimal. sc1 asm stores
//    regressed (sched fences); reverted.
//  * Transpose pass is structure-invariant ~190 us across 4 variants ->
//    ELIMINATED structurally this round.
//  * MONO-KERNEL, SOFT LEVEL-LOCKSTEP: 1024 blocks x 256 thr, all
//    co-resident (4 blocks/CU: LDS 33 KB x 4 <= 160 KB; launch_bounds
//    (256,4) caps VGPR <= 128 -> 16 waves/CU). Every block loops levels
//    0..15 internally; since all blocks are resident and start together,
//    they sweep levels in soft lockstep -> in-flight working set stays
//    1-2 tables (the R3 locality win) WITHOUT blockIdx.y banding.
//    Per 262144-pt chunk: gather 16 levels into per-thread LDS column
//    ([16][257] f32x2, conflict-free), then LDS-transposed coalesced
//    16 B/lane output stores. 1-deep level pipeline (ping-pong A/B)
//    keeps 16 loads in flight per thread (= R7 concurrency).
//    No workspace, no transpose dispatch, ws round-trip (256 MB) gone.
//  * Falsifier: FETCH >= 1 GB => lockstep drift destroyed locality =>
//    next: cooperative grid-sync per level or revert to R7 two-pass.

namespace {

using f32x2 = __attribute__((ext_vector_type(2))) float;
using f32x4 = __attribute__((ext_vector_type(4))) float;

// Global corner indices + interp factors for one level.
__device__ __forceinline__ void level_setup_g(
    float x, float y, float z, uint32_t l,
    uint32_t g[8], float f[6]) {
  uint32_t res = 16u << l;
  float scale = (float)res - 1.0f;
  float px = x * scale + 0.5f;
  float py = y * scale + 0.5f;
  float pz = z * scale + 0.5f;
  float gx = floorf(px), gy = floorf(py), gz = floorf(pz);
  float rx = px - gx, ry = py - gy, rz = pz - gz;
  uint32_t ix = (uint32_t)gx, iy = (uint32_t)gy, iz = (uint32_t)gz;

  if (l >= 3u) {
    uint32_t off = l * 524288u - 1257368u;
    const uint32_t P2 = 2654435761u, P3 = 805459861u;
    uint32_t hy0 = iy * P2, hy1 = hy0 + P2;
    uint32_t hz0 = iz * P3, hz1 = hz0 + P3;
    uint32_t hb[4] = {hy0 ^ hz0, hy1 ^ hz0, hy0 ^ hz1, hy1 ^ hz1};
    uint32_t ix1 = ix + 1u;
#pragma unroll
    for (int j = 0; j < 4; ++j) {
      g[2 * j]     = ((ix  ^ hb[j]) & 0x7FFFFu) + off;
      g[2 * j + 1] = ((ix1 ^ hb[j]) & 0x7FFFFu) + off;
    }
  } else {
    uint32_t off = (l == 0u) ? 0u : ((l == 1u) ? 4920u : 40864u);
    uint32_t base = res + 1u;
    uint32_t bb = base * base;
    uint32_t dy0 = iy * base, dy1 = dy0 + base;
    uint32_t dz0 = iz * bb,   dz1 = dz0 + bb;
#pragma unroll
    for (int c = 0; c < 8; ++c) {
      g[c] = ix + (uint32_t)(c & 1) +
             ((c & 2) ? dy1 : dy0) + ((c & 4) ? dz1 : dz0) + off;
    }
  }
  f[0] = 1.0f - rx; f[1] = rx;
  f[2] = 1.0f - ry; f[3] = ry;
  f[4] = 1.0f - rz; f[5] = rz;
}

__device__ __forceinline__ f32x2 interp8(const f32x2 e[8], const float f[6]) {
  float o0 = 0.0f, o1 = 0.0f;
#pragma unroll
  for (int c = 0; c < 8; ++c) {
    float w = f[c & 1] * f[2 + ((c >> 1) & 1)] * f[4 + ((c >> 2) & 1)];
    o0 = fmaf(w, e[c].x, o0);
    o1 = fmaf(w, e[c].y, o1);
  }
  f32x2 r; r.x = o0; r.y = o1;
  return r;
}

// ---- Mono-kernel: all 16 levels per block, LDS transpose, one dispatch ----
__global__ __launch_bounds__(256, 4) void grid_encode_mono(
    const float* __restrict__ in,    // [B,3] in [-1,1]
    const f32x2* __restrict__ emb,   // [7131240] float2
    f32x4* __restrict__ out,         // [B*8] f32x4 == [B,16,2] floats
    uint32_t B, uint32_t sweep, uint32_t nchunk) {
  __shared__ f32x2 lds[16 * 257];    // [level][point-in-block], pad 257
  uint32_t tid = threadIdx.x;

  for (uint32_t c = 0; c < nchunk; ++c) {
    uint32_t cb = c * sweep + blockIdx.x * 256u;  // block's first point
    uint32_t p = cb + tid;
    uint32_t pc = (p < B) ? p : (B - 1u);

    // nt input loads: streamed once, keep out of table-holding caches
    float x = (__builtin_nontemporal_load(&in[pc * 3 + 0]) + 1.0f) * 0.5f;
    float y = (__builtin_nontemporal_load(&in[pc * 3 + 1]) + 1.0f) * 0.5f;
    float z = (__builtin_nontemporal_load(&in[pc * 3 + 2]) + 1.0f) * 0.5f;

    // ---- gather all 16 levels, 1-deep software pipeline (ping-pong) ----
    uint32_t gA[8]; float fA[6];
    level_setup_g(x, y, z, 0u, gA, fA);
    f32x2 eA[8];
#pragma unroll
    for (int k = 0; k < 8; ++k) eA[k] = emb[gA[k]];

#pragma unroll 1
    for (uint32_t lp = 0; lp < 8u; ++lp) {
      uint32_t l0 = 2u * lp, l1 = l0 + 1u;

      // issue level l1 while l0's loads are in flight
      uint32_t gB[8]; float fB[6];
      level_setup_g(x, y, z, l1, gB, fB);
      f32x2 eB[8];
#pragma unroll
      for (int k = 0; k < 8; ++k) eB[k] = emb[gB[k]];

      // consume l0
      lds[l0 * 257u + tid] = interp8(eA, fA);

      // issue level l0+2 while l1's loads are in flight
      if (lp < 7u) {
        level_setup_g(x, y, z, l0 + 2u, gA, fA);
#pragma unroll
        for (int k = 0; k < 8; ++k) eA[k] = emb[gA[k]];
      }

      // consume l1
      lds[l1 * 257u + tid] = interp8(eB, fB);
    }

    __syncthreads();

    // ---- coalesced output: thread -> linear f32x4, via LDS transpose ----
    // lin = m*256+tid; q = point-in-block, j = level-pair. Consecutive
    // lanes write consecutive 16 B (full-line stores). LDS reads spread
    // over banks via pad-257 (2-way max = free).
#pragma unroll
    for (uint32_t m = 0; m < 8u; ++m) {
      uint32_t lin = m * 256u + tid;
      uint32_t q = lin >> 3, j = lin & 7u;
      if (cb + q < B) {
        f32x2 a = lds[(2u * j)      * 257u + q];
        f32x2 b = lds[(2u * j + 1u) * 257u + q];
        f32x4 v = {a.x, a.y, b.x, b.y};
        __builtin_nontemporal_store(v, &out[(size_t)(cb + q) * 8u + j]);
      }
    }

    __syncthreads();   // protect lds before next chunk's fill
  }
}

}  // namespace

extern "C" void kernel_launch(void* const* d_in, const int* in_sizes, int n_in,
                              void* d_out, int out_size, void* d_ws, size_t ws_size,
                              hipStream_t stream) {
  (void)n_in; (void)out_size; (void)d_ws; (void)ws_size;
  const float* in = (const float*)d_in[0];
  const f32x2* emb = (const f32x2*)d_in[1];
  f32x4* out = (f32x4*)d_out;
  uint32_t B = (uint32_t)(in_sizes[0] / 3);

  // Fully co-resident grid: 1024 blocks = 4 blocks/CU x 256 CUs
  // (LDS 32.9 KB x 4 <= 160 KB, 16 waves/CU via launch_bounds(256,4)).
  uint32_t pblocks = (B + 255u) / 256u;
  uint32_t grid = pblocks < 1024u ? pblocks : 1024u;
  uint32_t sweep = grid * 256u;
  uint32_t nchunk = (B + sweep - 1u) / sweep;

  hipLaunchKernelGGL(grid_encode_mono, dim3(grid), dim3(256), 0, stream,
                     in, emb, out, B, sweep, nchunk);
}

// Round 7
// 899.474 us; speedup vs baseline: 1.0554x; 1.0554x over previous
//
#include <hip/hip_runtime.h>
#include <cstdint>

// GridEncoder forward (torch-ngp semantics), MI355X.
// B = 1048576 points, D=3, L=16 levels, C=2, H=16, per_level_scale=2.0,
// log2_hashmap_size=19, align_corners=False.
//
// Level metadata:
//   res(l)   = 16 << l, scale(l) = res - 1
//   dense levels 0,1,2: offsets 0, 4920, 40864, base = res+1,
//     idx = cx + cy*base + cz*base^2
//   hashed levels 3..15: size 2^19, idx = hash & 0x7FFFF,
//     offset(l) = l*524288 - 1257368
//   primes (1, 2654435761, 805459861)
//
// R10 theory of record:
//  * TCC == L2: FETCH_SIZE counts L2-miss bytes (R9's 2.96 GB = L2
//    thrash; soft lockstep drifted -> mono-kernel dead). R7's 565 MB =
//    8 XCDs x band table (~416 MB) + 16x input re-read (192 MB): the
//    blockIdx.y banding gives ~93% L2 gather hits. KEEP IT.
//  * Gather wall: throughput = outstanding-vmem-slots / L2 latency ~
//    0.55 lane-req/cy/CU -> 134M requests = ~395 us. R5 (fewer req),
//    R7 (more conc), R8 (wider loads) all confirm the wall. Gather is
//    AT its floor; 8 B diverged dwordx2 loads, nt everything streaming.
//  * R10: DELETE the 190 us transpose pass by storing gather results
//    DIRECTLY to out[p*16+l] (nt f32x2, stride 128 B across lanes).
//    Pays +16.8M diverged store requests (+12% on the request wall,
//    ~+45 us) and ~4x write-sector amplification (WRITE ~0.5 GB,
//    absorbed: HBM is at 18%) to save the whole 190 us pass + 268 MB
//    ws round-trip. nt stores -> no L2 write-allocate -> tables stay
//    resident (R6's failure mode avoided).

namespace {

using f32x2 = __attribute__((ext_vector_type(2))) float;
using f32x4 = __attribute__((ext_vector_type(4))) float;

// Global corner indices + interp factors for one level.
__device__ __forceinline__ void level_setup_g(
    float x, float y, float z, uint32_t l,
    uint32_t g[8], float f[6]) {
  uint32_t res = 16u << l;
  float scale = (float)res - 1.0f;
  float px = x * scale + 0.5f;
  float py = y * scale + 0.5f;
  float pz = z * scale + 0.5f;
  float gx = floorf(px), gy = floorf(py), gz = floorf(pz);
  float rx = px - gx, ry = py - gy, rz = pz - gz;
  uint32_t ix = (uint32_t)gx, iy = (uint32_t)gy, iz = (uint32_t)gz;

  if (l >= 3u) {
    uint32_t off = l * 524288u - 1257368u;
    const uint32_t P2 = 2654435761u, P3 = 805459861u;
    uint32_t hy0 = iy * P2, hy1 = hy0 + P2;
    uint32_t hz0 = iz * P3, hz1 = hz0 + P3;
    uint32_t hb[4] = {hy0 ^ hz0, hy1 ^ hz0, hy0 ^ hz1, hy1 ^ hz1};
    uint32_t ix1 = ix + 1u;
#pragma unroll
    for (int j = 0; j < 4; ++j) {
      g[2 * j]     = ((ix  ^ hb[j]) & 0x7FFFFu) + off;
      g[2 * j + 1] = ((ix1 ^ hb[j]) & 0x7FFFFu) + off;
    }
  } else {
    uint32_t off = (l == 0u) ? 0u : ((l == 1u) ? 4920u : 40864u);
    uint32_t base = res + 1u;
    uint32_t bb = base * base;
    uint32_t dy0 = iy * base, dy1 = dy0 + base;
    uint32_t dz0 = iz * bb,   dz1 = dz0 + bb;
#pragma unroll
    for (int c = 0; c < 8; ++c) {
      g[c] = ix + (uint32_t)(c & 1) +
             ((c & 2) ? dy1 : dy0) + ((c & 4) ? dz1 : dz0) + off;
    }
  }
  f[0] = 1.0f - rx; f[1] = rx;
  f[2] = 1.0f - ry; f[3] = ry;
  f[4] = 1.0f - rz; f[5] = rz;
}

__device__ __forceinline__ f32x2 interp8(const f32x2 e[8], const float f[6]) {
  float o0 = 0.0f, o1 = 0.0f;
#pragma unroll
  for (int c = 0; c < 8; ++c) {
    float w = f[c & 1] * f[2 + ((c >> 1) & 1)] * f[4 + ((c >> 2) & 1)];
    o0 = fmaf(w, e[c].x, o0);
    o1 = fmaf(w, e[c].y, o1);
  }
  f32x2 r; r.x = o0; r.y = o1;
  return r;
}

// ---- Pass 0: normalize inputs into planar X,Y,Z (12 MiB) ----
__global__ __launch_bounds__(256) void prep_xyz_kernel(
    const float* __restrict__ in,    // [B,3] in [-1,1]
    float* __restrict__ X, float* __restrict__ Y, float* __restrict__ Z,
    uint32_t B) {
  uint32_t t = blockIdx.x * 256u + threadIdx.x;
  uint32_t nquad = B >> 2;          // B % 4 == 0 guaranteed by launcher
  if (t >= nquad) return;
  const f32x4* in4 = reinterpret_cast<const f32x4*>(in);
  f32x4 q0 = __builtin_nontemporal_load(&in4[t * 3 + 0]);
  f32x4 q1 = __builtin_nontemporal_load(&in4[t * 3 + 1]);
  f32x4 q2 = __builtin_nontemporal_load(&in4[t * 3 + 2]);
  f32x4 xv = {q0.x, q0.w, q1.z, q2.y};
  f32x4 yv = {q0.y, q1.x, q1.w, q2.z};
  f32x4 zv = {q0.z, q1.y, q2.x, q2.w};
  xv = (xv + 1.0f) * 0.5f;
  yv = (yv + 1.0f) * 0.5f;
  zv = (zv + 1.0f) * 0.5f;
  reinterpret_cast<f32x4*>(X)[t] = xv;
  reinterpret_cast<f32x4*>(Y)[t] = yv;
  reinterpret_cast<f32x4*>(Z)[t] = zv;
}

// ---- Pass 1: level-phased gather, 2 pts/thread, DIRECT out stores ----
template <bool XYZ>
__global__ __launch_bounds__(256, 5) void gather_direct_kernel(
    const float* __restrict__ in,
    const float* __restrict__ X, const float* __restrict__ Y,
    const float* __restrict__ Z,
    const f32x2* __restrict__ emb,     // [7131240] float2
    f32x2* __restrict__ out,           // [B*16] f32x2 == [B,16,2] floats
    uint32_t B) {
  uint32_t l = blockIdx.y;                       // level: slowest dispatch dim
  uint32_t p0 = blockIdx.x * 512u + threadIdx.x;
  uint32_t p1 = p0 + 256u;
  bool vA = p0 < B, vB = p1 < B;
  if (!vA) return;
  uint32_t p1c = vB ? p1 : p0;

  // nt XYZ reads: streaming per band, keep out of table-holding L2
  float xA, yA, zA, xB, yB, zB;
  if (XYZ) {
    xA = __builtin_nontemporal_load(&X[p0]);
    yA = __builtin_nontemporal_load(&Y[p0]);
    zA = __builtin_nontemporal_load(&Z[p0]);
    xB = __builtin_nontemporal_load(&X[p1c]);
    yB = __builtin_nontemporal_load(&Y[p1c]);
    zB = __builtin_nontemporal_load(&Z[p1c]);
  } else {
    xA = (__builtin_nontemporal_load(&in[p0 * 3 + 0]) + 1.0f) * 0.5f;
    yA = (__builtin_nontemporal_load(&in[p0 * 3 + 1]) + 1.0f) * 0.5f;
    zA = (__builtin_nontemporal_load(&in[p0 * 3 + 2]) + 1.0f) * 0.5f;
    xB = (__builtin_nontemporal_load(&in[p1c * 3 + 0]) + 1.0f) * 0.5f;
    yB = (__builtin_nontemporal_load(&in[p1c * 3 + 1]) + 1.0f) * 0.5f;
    zB = (__builtin_nontemporal_load(&in[p1c * 3 + 2]) + 1.0f) * 0.5f;
  }

  // --- issue A's 8 gathers (8 B diverged dwordx2: proven optimal) ---
  uint32_t gA[8]; float fA[6];
  level_setup_g(xA, yA, zA, l, gA, fA);
  f32x2 eA[8];
#pragma unroll
  for (int c = 0; c < 8; ++c) eA[c] = emb[gA[c]];

  // --- issue B's 8 gathers (overlap A's latency) ---
  uint32_t gB[8]; float fB[6];
  level_setup_g(xB, yB, zB, l, gB, fB);
  f32x2 eB[8];
#pragma unroll
  for (int c = 0; c < 8; ++c) eB[c] = emb[gB[c]];

  // --- consume; nt diverged stores straight to final layout ---
  f32x2 rA = interp8(eA, fA);
  __builtin_nontemporal_store(rA, &out[(size_t)p0 * 16u + l]);
  if (vB) {
    f32x2 rB = interp8(eB, fB);
    __builtin_nontemporal_store(rB, &out[(size_t)p1 * 16u + l]);
  }
}

// ---- Fallback (B % 4 != 0): single-pass kernel ----
__global__ __launch_bounds__(256) void grid_encode_fallback(
    const float* __restrict__ in, const f32x2* __restrict__ emb,
    f32x2* __restrict__ out, uint32_t B) {
  uint32_t p = blockIdx.x * 256u + threadIdx.x;
  if (p >= B) return;
  float x = (in[p * 3 + 0] + 1.0f) * 0.5f;
  float y = (in[p * 3 + 1] + 1.0f) * 0.5f;
  float z = (in[p * 3 + 2] + 1.0f) * 0.5f;
#pragma unroll 1
  for (uint32_t l = 0; l < 16u; ++l) {
    uint32_t g[8]; float f[6];
    level_setup_g(x, y, z, l, g, f);
    f32x2 e[8];
#pragma unroll
    for (int c = 0; c < 8; ++c) e[c] = emb[g[c]];
    out[(size_t)p * 16u + l] = interp8(e, f);
  }
}

}  // namespace

extern "C" void kernel_launch(void* const* d_in, const int* in_sizes, int n_in,
                              void* d_out, int out_size, void* d_ws, size_t ws_size,
                              hipStream_t stream) {
  (void)n_in; (void)out_size;
  const float* in = (const float*)d_in[0];
  const f32x2* emb = (const f32x2*)d_in[1];
  f32x2* out = (f32x2*)d_out;
  uint32_t B = (uint32_t)(in_sizes[0] / 3);

  size_t xyz_bytes = (size_t)3 * B * sizeof(float);   // 12 MiB at B=1M

  if ((B % 4u) == 0u) {
    uint32_t gblocks = (B + 511u) / 512u;
    bool use_xyz = ws_size >= xyz_bytes;
    if (use_xyz) {
      float* X = (float*)d_ws;
      float* Y = X + B;
      float* Z = Y + B;
      uint32_t pblocks = ((B >> 2) + 255u) / 256u;
      hipLaunchKernelGGL(prep_xyz_kernel, dim3(pblocks), dim3(256), 0, stream,
                         in, X, Y, Z, B);
      hipLaunchKernelGGL((gather_direct_kernel<true>), dim3(gblocks, 16),
                         dim3(256), 0, stream, in, X, Y, Z, emb, out, B);
    } else {
      hipLaunchKernelGGL((gather_direct_kernel<false>), dim3(gblocks, 16),
                         dim3(256), 0, stream, in, nullptr, nullptr, nullptr,
                         emb, out, B);
    }
  } else {
    uint32_t pblocks = (B + 255u) / 256u;
    hipLaunchKernelGGL(grid_encode_fallback, dim3(pblocks), dim3(256), 0,
                       stream, in, emb, out, B);
  }
}

// Round 8
// 619.935 us; speedup vs baseline: 1.5313x; 1.4509x over previous
//
#include <hip/hip_runtime.h>
#include <cstdint>

// GridEncoder forward (torch-ngp semantics), MI355X.
// B = 1048576 points, D=3, L=16 levels, C=2, H=16, per_level_scale=2.0,
// log2_hashmap_size=19, align_corners=False.
//
// Level metadata:
//   res(l)   = 16 << l, scale(l) = res - 1
//   dense levels 0,1,2: offsets 0, 4920, 40864, base = res+1,
//     idx = cx + cy*base + cz*base^2
//   hashed levels 3..15: size 2^19, idx = hash & 0x7FFFF,
//     offset(l) = l*524288 - 1257368
//   primes (1, 2654435761, 805459861)
//
// R11 theory of record (ledger of killed branches):
//  * Gather: AT the diverged-load wall (~0.55 lane-req/cy/CU).
//    Killed levers: fewer requests (R5), wider loads (R8: bytes are the
//    currency, 8 B dwordx2 optimal), more concurrency (R7: -6% only),
//    direct diverged stores (R10: +385 us, stores ~10x cost of loads),
//    mono-kernel soft lockstep (R9: drift -> L2 thrash, FETCH 2.9 GB).
//    KEEP R7's gather verbatim: blockIdx.y level bands (93% L2 hit),
//    2 pts/thread, nt streaming loads, nt coalesced ws stores.
//  * Transpose: 1.4 TB/s, structure-invariant across 4 access shapes.
//    Last untested variable: the NT OUTPUT STORES. nt was inherited from
//    the gather's table-protection constraint, but the transpose runs
//    after all gathers: nothing to protect. R10 showed the nt diverged
//    store path is pathological; hypothesis: nt coalesced stores also
//    ride a slow non-combining path. This round: LDS transpose with
//    f32x4 reads (1 KB/wave-inst) and REGULAR f32x4 stores.
//  * Falsifier: transpose residual >= 170 us => nt-store hypothesis
//    dead => both passes at verified walls => roofline call next.

namespace {

using f32x2 = __attribute__((ext_vector_type(2))) float;
using f32x4 = __attribute__((ext_vector_type(4))) float;

// Global corner indices + interp factors for one level.
__device__ __forceinline__ void level_setup_g(
    float x, float y, float z, uint32_t l,
    uint32_t g[8], float f[6]) {
  uint32_t res = 16u << l;
  float scale = (float)res - 1.0f;
  float px = x * scale + 0.5f;
  float py = y * scale + 0.5f;
  float pz = z * scale + 0.5f;
  float gx = floorf(px), gy = floorf(py), gz = floorf(pz);
  float rx = px - gx, ry = py - gy, rz = pz - gz;
  uint32_t ix = (uint32_t)gx, iy = (uint32_t)gy, iz = (uint32_t)gz;

  if (l >= 3u) {
    uint32_t off = l * 524288u - 1257368u;
    const uint32_t P2 = 2654435761u, P3 = 805459861u;
    uint32_t hy0 = iy * P2, hy1 = hy0 + P2;
    uint32_t hz0 = iz * P3, hz1 = hz0 + P3;
    uint32_t hb[4] = {hy0 ^ hz0, hy1 ^ hz0, hy0 ^ hz1, hy1 ^ hz1};
    uint32_t ix1 = ix + 1u;
#pragma unroll
    for (int j = 0; j < 4; ++j) {
      g[2 * j]     = ((ix  ^ hb[j]) & 0x7FFFFu) + off;
      g[2 * j + 1] = ((ix1 ^ hb[j]) & 0x7FFFFu) + off;
    }
  } else {
    uint32_t off = (l == 0u) ? 0u : ((l == 1u) ? 4920u : 40864u);
    uint32_t base = res + 1u;
    uint32_t bb = base * base;
    uint32_t dy0 = iy * base, dy1 = dy0 + base;
    uint32_t dz0 = iz * bb,   dz1 = dz0 + bb;
#pragma unroll
    for (int c = 0; c < 8; ++c) {
      g[c] = ix + (uint32_t)(c & 1) +
             ((c & 2) ? dy1 : dy0) + ((c & 4) ? dz1 : dz0) + off;
    }
  }
  f[0] = 1.0f - rx; f[1] = rx;
  f[2] = 1.0f - ry; f[3] = ry;
  f[4] = 1.0f - rz; f[5] = rz;
}

__device__ __forceinline__ f32x2 interp8(const f32x2 e[8], const float f[6]) {
  float o0 = 0.0f, o1 = 0.0f;
#pragma unroll
  for (int c = 0; c < 8; ++c) {
    float w = f[c & 1] * f[2 + ((c >> 1) & 1)] * f[4 + ((c >> 2) & 1)];
    o0 = fmaf(w, e[c].x, o0);
    o1 = fmaf(w, e[c].y, o1);
  }
  f32x2 r; r.x = o0; r.y = o1;
  return r;
}

// ---- Pass 0: normalize inputs into planar X,Y,Z (12 MiB) ----
__global__ __launch_bounds__(256) void prep_xyz_kernel(
    const float* __restrict__ in,    // [B,3] in [-1,1]
    float* __restrict__ X, float* __restrict__ Y, float* __restrict__ Z,
    uint32_t B) {
  uint32_t t = blockIdx.x * 256u + threadIdx.x;
  uint32_t nquad = B >> 2;          // B % 4 == 0 guaranteed by launcher
  if (t >= nquad) return;
  const f32x4* in4 = reinterpret_cast<const f32x4*>(in);
  f32x4 q0 = __builtin_nontemporal_load(&in4[t * 3 + 0]);
  f32x4 q1 = __builtin_nontemporal_load(&in4[t * 3 + 1]);
  f32x4 q2 = __builtin_nontemporal_load(&in4[t * 3 + 2]);
  f32x4 xv = {q0.x, q0.w, q1.z, q2.y};
  f32x4 yv = {q0.y, q1.x, q1.w, q2.z};
  f32x4 zv = {q0.z, q1.y, q2.x, q2.w};
  xv = (xv + 1.0f) * 0.5f;
  yv = (yv + 1.0f) * 0.5f;
  zv = (zv + 1.0f) * 0.5f;
  reinterpret_cast<f32x4*>(X)[t] = xv;
  reinterpret_cast<f32x4*>(Y)[t] = yv;
  reinterpret_cast<f32x4*>(Z)[t] = zv;
}

// ---- Pass 1: level-phased gather (R7 verbatim, proven 395 us) ----
template <bool XYZ>
__global__ __launch_bounds__(256, 5) void gather_lm_kernel(
    const float* __restrict__ in,
    const float* __restrict__ X, const float* __restrict__ Y,
    const float* __restrict__ Z,
    const f32x2* __restrict__ emb,     // [7131240] float2
    f32x2* __restrict__ ws,            // [16*B] float2, level-major
    uint32_t B) {
  uint32_t l = blockIdx.y;                       // level: slowest dispatch dim
  uint32_t p0 = blockIdx.x * 512u + threadIdx.x;
  uint32_t p1 = p0 + 256u;
  bool vA = p0 < B, vB = p1 < B;
  if (!vA) return;
  uint32_t p1c = vB ? p1 : p0;

  // nt XYZ reads: streaming per band, keep out of table-holding L2
  float xA, yA, zA, xB, yB, zB;
  if (XYZ) {
    xA = __builtin_nontemporal_load(&X[p0]);
    yA = __builtin_nontemporal_load(&Y[p0]);
    zA = __builtin_nontemporal_load(&Z[p0]);
    xB = __builtin_nontemporal_load(&X[p1c]);
    yB = __builtin_nontemporal_load(&Y[p1c]);
    zB = __builtin_nontemporal_load(&Z[p1c]);
  } else {
    xA = (__builtin_nontemporal_load(&in[p0 * 3 + 0]) + 1.0f) * 0.5f;
    yA = (__builtin_nontemporal_load(&in[p0 * 3 + 1]) + 1.0f) * 0.5f;
    zA = (__builtin_nontemporal_load(&in[p0 * 3 + 2]) + 1.0f) * 0.5f;
    xB = (__builtin_nontemporal_load(&in[p1c * 3 + 0]) + 1.0f) * 0.5f;
    yB = (__builtin_nontemporal_load(&in[p1c * 3 + 1]) + 1.0f) * 0.5f;
    zB = (__builtin_nontemporal_load(&in[p1c * 3 + 2]) + 1.0f) * 0.5f;
  }

  // --- issue A's 8 gathers (8 B diverged dwordx2: proven optimal) ---
  uint32_t gA[8]; float fA[6];
  level_setup_g(xA, yA, zA, l, gA, fA);
  f32x2 eA[8];
#pragma unroll
  for (int c = 0; c < 8; ++c) eA[c] = emb[gA[c]];

  // --- issue B's 8 gathers (overlap A's latency) ---
  uint32_t gB[8]; float fB[6];
  level_setup_g(xB, yB, zB, l, gB, fB);
  f32x2 eB[8];
#pragma unroll
  for (int c = 0; c < 8; ++c) eB[c] = emb[gB[c]];

  // --- consume; nt coalesced ws stores (protect table L2 residency) ---
  f32x2 rA = interp8(eA, fA);
  __builtin_nontemporal_store(rA, &ws[(size_t)l * B + p0]);
  if (vB) {
    f32x2 rB = interp8(eB, fB);
    __builtin_nontemporal_store(rB, &ws[(size_t)l * B + p1]);
  }
}

// ---- Pass 2: LDS transpose, f32x4 reads, REGULAR f32x4 stores ----
// 256 points per block. Load: 16 rows x 128 f32x4, 8/thread, each
// wave-inst reads 1 KB contiguous from one row. Store: 8/thread, each
// wave-inst writes 1 KB contiguous; REGULAR stores (nothing to protect
// after gathers; nt suspected as the 1.4 TB/s wall).
__global__ __launch_bounds__(256) void transpose_lds_kernel(
    const f32x2* __restrict__ ws,   // [16*B] level-major
    f32x4* __restrict__ out,        // [B*8] float4 == [B,16,2] floats
    uint32_t B) {
  __shared__ f32x4 lds4[16][129];   // pad 129 to spread banks
  uint32_t tid = threadIdx.x;
  uint32_t cb = blockIdx.x * 256u;  // block's first point (B%256==0)

  const f32x4* ws4 = reinterpret_cast<const f32x4*>(ws);
#pragma unroll
  for (uint32_t m = 0; m < 8u; ++m) {
    uint32_t lin = m * 256u + tid;
    uint32_t row = lin >> 7;        // 0..15
    uint32_t pos = lin & 127u;      // f32x4 within row-tile
    lds4[row][pos] = ws4[(((size_t)row * B + cb) >> 1) + pos];
  }
  __syncthreads();

  const f32x2* lds2 = reinterpret_cast<const f32x2*>(lds4);
#pragma unroll
  for (uint32_t m = 0; m < 8u; ++m) {
    uint32_t lin = m * 256u + tid;
    uint32_t q = lin >> 3;          // point in block
    uint32_t j = lin & 7u;          // level pair
    f32x2 a = lds2[(2u * j)      * 258u + q];
    f32x2 b = lds2[(2u * j + 1u) * 258u + q];
    f32x4 v = {a.x, a.y, b.x, b.y};
    out[(size_t)(cb + q) * 8u + j] = v;   // REGULAR store
  }
}

// ---- Fallback (B % 256 != 0 or ws too small): single-pass kernel ----
__global__ __launch_bounds__(256) void grid_encode_fallback(
    const float* __restrict__ in, const f32x2* __restrict__ emb,
    f32x2* __restrict__ out, uint32_t B) {
  uint32_t p = blockIdx.x * 256u + threadIdx.x;
  if (p >= B) return;
  float x = (in[p * 3 + 0] + 1.0f) * 0.5f;
  float y = (in[p * 3 + 1] + 1.0f) * 0.5f;
  float z = (in[p * 3 + 2] + 1.0f) * 0.5f;
#pragma unroll 1
  for (uint32_t l = 0; l < 16u; ++l) {
    uint32_t g[8]; float f[6];
    level_setup_g(x, y, z, l, g, f);
    f32x2 e[8];
#pragma unroll
    for (int c = 0; c < 8; ++c) e[c] = emb[g[c]];
    out[(size_t)p * 16u + l] = interp8(e, f);
  }
}

}  // namespace

extern "C" void kernel_launch(void* const* d_in, const int* in_sizes, int n_in,
                              void* d_out, int out_size, void* d_ws, size_t ws_size,
                              hipStream_t stream) {
  (void)n_in; (void)out_size;
  const float* in = (const float*)d_in[0];
  const f32x2* emb = (const f32x2*)d_in[1];
  uint32_t B = (uint32_t)(in_sizes[0] / 3);

  size_t ws_lm   = (size_t)16 * B * sizeof(f32x2);          // 128 MiB at B=1M
  size_t ws_full = ws_lm + (size_t)3 * B * sizeof(float);   // + 12 MiB xyz

  if ((B % 256u) == 0u && ws_size >= ws_lm) {
    f32x2* ws = (f32x2*)d_ws;
    uint32_t gblocks = (B + 511u) / 512u;
    bool use_xyz = ws_size >= ws_full;
    if (use_xyz) {
      float* X = (float*)((char*)d_ws + ws_lm);
      float* Y = X + B;
      float* Z = Y + B;
      uint32_t pblocks = ((B >> 2) + 255u) / 256u;
      hipLaunchKernelGGL(prep_xyz_kernel, dim3(pblocks), dim3(256), 0, stream,
                         in, X, Y, Z, B);
      hipLaunchKernelGGL((gather_lm_kernel<true>), dim3(gblocks, 16), dim3(256),
                         0, stream, in, X, Y, Z, emb, ws, B);
    } else {
      hipLaunchKernelGGL((gather_lm_kernel<false>), dim3(gblocks, 16), dim3(256),
                         0, stream, in, nullptr, nullptr, nullptr, emb, ws, B);
    }
    uint32_t tblocks = B / 256u;
    hipLaunchKernelGGL(transpose_lds_kernel, dim3(tblocks), dim3(256), 0,
                       stream, ws, (f32x4*)d_out, B);
  } else {
    uint32_t pblocks = (B + 255u) / 256u;
    hipLaunchKernelGGL(grid_encode_fallback, dim3(pblocks), dim3(256), 0,
                       stream, in, emb, (f32x2*)d_out, B);
  }
}

// Round 9
// 603.168 us; speedup vs baseline: 1.5739x; 1.0278x over previous
//
#include <hip/hip_runtime.h>
#include <cstdint>

// GridEncoder forward (torch-ngp semantics), MI355X.
// B = 1048576 points, D=3, L=16 levels, C=2, H=16, per_level_scale=2.0,
// log2_hashmap_size=19, align_corners=False.
//
// Level metadata:
//   res(l)   = 16 << l, scale(l) = res - 1
//   dense levels 0,1,2: offsets 0, 4920, 40864, base = res+1,
//     idx = cx + cy*base + cz*base^2
//   hashed levels 3..15: size 2^19, idx = hash & 0x7FFFF,
//     offset(l) = l*524288 - 1257368
//   primes (1, 2654435761, 805459861)
//
// R12 theory of record (ledger):
//  * Gather (421 us): AT the diverged-load wall (~0.55 lane-req/cy/CU,
//    invariant across 5 structures). Killed levers: fewer requests (R5),
//    16 B loads (R8: bytes are the currency), more concurrency (R7: -6%),
//    direct diverged stores (R10: +385 us), regular ws stores (R6: table
//    eviction, FETCH +15%), mono-kernel (R9: lockstep drift, FETCH 2.9GB).
//    UNCHANGED this round except the ws store ADDRESS.
//  * Transpose (187 us, 1.4 TB/s): invariant across 5 access shapes and
//    all cache-flag combos. Last untested variable vs the 6.3 TB/s copy
//    ubench: STREAM COUNT. All variants read ws as 16 interleaved row
//    streams/block (~16K concurrent streams machine-wide, 2 KB segments).
//    R12: ws becomes CHUNK-MAJOR - all 16 levels of each 256-pt chunk
//    contiguous (32 KB) - so the transpose reads ONE contiguous stream
//    per block and writes one. Both sides copy-equivalent.
//    Gather store coalescing is unchanged (contiguous 512 B/wave).
//  * Falsifier (pre-committed): total >= 600 us => transpose is
//    memcpy-equivalent yet stuck => wall outside kernel control =>
//    declare ROOFLINE next round.

namespace {

using f32x2 = __attribute__((ext_vector_type(2))) float;
using f32x4 = __attribute__((ext_vector_type(4))) float;

// Global corner indices + interp factors for one level.
__device__ __forceinline__ void level_setup_g(
    float x, float y, float z, uint32_t l,
    uint32_t g[8], float f[6]) {
  uint32_t res = 16u << l;
  float scale = (float)res - 1.0f;
  float px = x * scale + 0.5f;
  float py = y * scale + 0.5f;
  float pz = z * scale + 0.5f;
  float gx = floorf(px), gy = floorf(py), gz = floorf(pz);
  float rx = px - gx, ry = py - gy, rz = pz - gz;
  uint32_t ix = (uint32_t)gx, iy = (uint32_t)gy, iz = (uint32_t)gz;

  if (l >= 3u) {
    uint32_t off = l * 524288u - 1257368u;
    const uint32_t P2 = 2654435761u, P3 = 805459861u;
    uint32_t hy0 = iy * P2, hy1 = hy0 + P2;
    uint32_t hz0 = iz * P3, hz1 = hz0 + P3;
    uint32_t hb[4] = {hy0 ^ hz0, hy1 ^ hz0, hy0 ^ hz1, hy1 ^ hz1};
    uint32_t ix1 = ix + 1u;
#pragma unroll
    for (int j = 0; j < 4; ++j) {
      g[2 * j]     = ((ix  ^ hb[j]) & 0x7FFFFu) + off;
      g[2 * j + 1] = ((ix1 ^ hb[j]) & 0x7FFFFu) + off;
    }
  } else {
    uint32_t off = (l == 0u) ? 0u : ((l == 1u) ? 4920u : 40864u);
    uint32_t base = res + 1u;
    uint32_t bb = base * base;
    uint32_t dy0 = iy * base, dy1 = dy0 + base;
    uint32_t dz0 = iz * bb,   dz1 = dz0 + bb;
#pragma unroll
    for (int c = 0; c < 8; ++c) {
      g[c] = ix + (uint32_t)(c & 1) +
             ((c & 2) ? dy1 : dy0) + ((c & 4) ? dz1 : dz0) + off;
    }
  }
  f[0] = 1.0f - rx; f[1] = rx;
  f[2] = 1.0f - ry; f[3] = ry;
  f[4] = 1.0f - rz; f[5] = rz;
}

__device__ __forceinline__ f32x2 interp8(const f32x2 e[8], const float f[6]) {
  float o0 = 0.0f, o1 = 0.0f;
#pragma unroll
  for (int c = 0; c < 8; ++c) {
    float w = f[c & 1] * f[2 + ((c >> 1) & 1)] * f[4 + ((c >> 2) & 1)];
    o0 = fmaf(w, e[c].x, o0);
    o1 = fmaf(w, e[c].y, o1);
  }
  f32x2 r; r.x = o0; r.y = o1;
  return r;
}

// ---- Pass 0: normalize inputs into planar X,Y,Z (12 MiB) ----
__global__ __launch_bounds__(256) void prep_xyz_kernel(
    const float* __restrict__ in,    // [B,3] in [-1,1]
    float* __restrict__ X, float* __restrict__ Y, float* __restrict__ Z,
    uint32_t B) {
  uint32_t t = blockIdx.x * 256u + threadIdx.x;
  uint32_t nquad = B >> 2;          // B % 4 == 0 guaranteed by launcher
  if (t >= nquad) return;
  const f32x4* in4 = reinterpret_cast<const f32x4*>(in);
  f32x4 q0 = __builtin_nontemporal_load(&in4[t * 3 + 0]);
  f32x4 q1 = __builtin_nontemporal_load(&in4[t * 3 + 1]);
  f32x4 q2 = __builtin_nontemporal_load(&in4[t * 3 + 2]);
  f32x4 xv = {q0.x, q0.w, q1.z, q2.y};
  f32x4 yv = {q0.y, q1.x, q1.w, q2.z};
  f32x4 zv = {q0.z, q1.y, q2.x, q2.w};
  xv = (xv + 1.0f) * 0.5f;
  yv = (yv + 1.0f) * 0.5f;
  zv = (zv + 1.0f) * 0.5f;
  reinterpret_cast<f32x4*>(X)[t] = xv;
  reinterpret_cast<f32x4*>(Y)[t] = yv;
  reinterpret_cast<f32x4*>(Z)[t] = zv;
}

// ---- Pass 1: level-phased gather, CHUNK-MAJOR ws stores ----
// ws layout: ws[(p>>8)*4096 + l*256 + (p&255)]  (f32x2 units)
// -> all 16 levels of a 256-point chunk are one contiguous 32 KB block.
// Per-wave store coalescing identical to level-major (contig 512 B).
template <bool XYZ>
__global__ __launch_bounds__(256, 5) void gather_cm_kernel(
    const float* __restrict__ in,
    const float* __restrict__ X, const float* __restrict__ Y,
    const float* __restrict__ Z,
    const f32x2* __restrict__ emb,     // [7131240] float2
    f32x2* __restrict__ ws,            // [16*B] float2, chunk-major
    uint32_t B) {
  uint32_t l = blockIdx.y;                       // level: slowest dispatch dim
  uint32_t p0 = blockIdx.x * 512u + threadIdx.x;
  uint32_t p1 = p0 + 256u;
  bool vA = p0 < B, vB = p1 < B;
  if (!vA) return;
  uint32_t p1c = vB ? p1 : p0;

  // nt XYZ reads: streaming per band, keep out of table-holding L2
  float xA, yA, zA, xB, yB, zB;
  if (XYZ) {
    xA = __builtin_nontemporal_load(&X[p0]);
    yA = __builtin_nontemporal_load(&Y[p0]);
    zA = __builtin_nontemporal_load(&Z[p0]);
    xB = __builtin_nontemporal_load(&X[p1c]);
    yB = __builtin_nontemporal_load(&Y[p1c]);
    zB = __builtin_nontemporal_load(&Z[p1c]);
  } else {
    xA = (__builtin_nontemporal_load(&in[p0 * 3 + 0]) + 1.0f) * 0.5f;
    yA = (__builtin_nontemporal_load(&in[p0 * 3 + 1]) + 1.0f) * 0.5f;
    zA = (__builtin_nontemporal_load(&in[p0 * 3 + 2]) + 1.0f) * 0.5f;
    xB = (__builtin_nontemporal_load(&in[p1c * 3 + 0]) + 1.0f) * 0.5f;
    yB = (__builtin_nontemporal_load(&in[p1c * 3 + 1]) + 1.0f) * 0.5f;
    zB = (__builtin_nontemporal_load(&in[p1c * 3 + 2]) + 1.0f) * 0.5f;
  }

  // --- issue A's 8 gathers (8 B diverged dwordx2: proven optimal) ---
  uint32_t gA[8]; float fA[6];
  level_setup_g(xA, yA, zA, l, gA, fA);
  f32x2 eA[8];
#pragma unroll
  for (int c = 0; c < 8; ++c) eA[c] = emb[gA[c]];

  // --- issue B's 8 gathers (overlap A's latency) ---
  uint32_t gB[8]; float fB[6];
  level_setup_g(xB, yB, zB, l, gB, fB);
  f32x2 eB[8];
#pragma unroll
  for (int c = 0; c < 8; ++c) eB[c] = emb[gB[c]];

  // --- consume; nt coalesced chunk-major ws stores ---
  f32x2 rA = interp8(eA, fA);
  __builtin_nontemporal_store(
      rA, &ws[(size_t)(p0 >> 8) * 4096u + l * 256u + (p0 & 255u)]);
  if (vB) {
    f32x2 rB = interp8(eB, fB);
    __builtin_nontemporal_store(
        rB, &ws[(size_t)(p1 >> 8) * 4096u + l * 256u + (p1 & 255u)]);
  }
}

// ---- Pass 2: chunk transpose, single-stream in, single-stream out ----
// Block c: read chunk c's 32 KB (ONE contiguous stream, 8 f32x4/thread),
// LDS transpose, write 32 KB contiguous point-major out. Copy-equivalent.
__global__ __launch_bounds__(256) void transpose_cm_kernel(
    const f32x2* __restrict__ ws,   // [16*B] chunk-major
    f32x4* __restrict__ out,        // [B*8] float4 == [B,16,2] floats
    uint32_t B) {
  __shared__ f32x4 lds4[16][129];   // [row][posx4], pad 129
  uint32_t tid = threadIdx.x;
  uint32_t cb = blockIdx.x * 256u;  // chunk base point (B%256==0)

  const f32x4* ch4 =
      reinterpret_cast<const f32x4*>(ws) + (size_t)blockIdx.x * 2048u;
#pragma unroll
  for (uint32_t m = 0; m < 8u; ++m) {
    uint32_t u = m * 256u + tid;    // contiguous over the whole 32 KB
    uint32_t row = u >> 7;          // level
    uint32_t pos = u & 127u;        // f32x4 within row
    lds4[row][pos] = __builtin_nontemporal_load(&ch4[u]);
  }
  __syncthreads();

  const f32x2* lds2 = reinterpret_cast<const f32x2*>(lds4);
#pragma unroll
  for (uint32_t m = 0; m < 8u; ++m) {
    uint32_t lin = m * 256u + tid;
    uint32_t q = lin >> 3;          // point in chunk
    uint32_t j = lin & 7u;          // level pair
    f32x2 a = lds2[(2u * j)      * 258u + q];
    f32x2 b = lds2[(2u * j + 1u) * 258u + q];
    f32x4 v = {a.x, a.y, b.x, b.y};
    out[(size_t)(cb + q) * 8u + j] = v;   // contiguous 1 KB per wave-inst
  }
}

// ---- Fallback (B % 256 != 0 or ws too small): single-pass kernel ----
__global__ __launch_bounds__(256) void grid_encode_fallback(
    const float* __restrict__ in, const f32x2* __restrict__ emb,
    f32x2* __restrict__ out, uint32_t B) {
  uint32_t p = blockIdx.x * 256u + threadIdx.x;
  if (p >= B) return;
  float x = (in[p * 3 + 0] + 1.0f) * 0.5f;
  float y = (in[p * 3 + 1] + 1.0f) * 0.5f;
  float z = (in[p * 3 + 2] + 1.0f) * 0.5f;
#pragma unroll 1
  for (uint32_t l = 0; l < 16u; ++l) {
    uint32_t g[8]; float f[6];
    level_setup_g(x, y, z, l, g, f);
    f32x2 e[8];
#pragma unroll
    for (int c = 0; c < 8; ++c) e[c] = emb[g[c]];
    out[(size_t)p * 16u + l] = interp8(e, f);
  }
}

}  // namespace

extern "C" void kernel_launch(void* const* d_in, const int* in_sizes, int n_in,
                              void* d_out, int out_size, void* d_ws, size_t ws_size,
                              hipStream_t stream) {
  (void)n_in; (void)out_size;
  const float* in = (const float*)d_in[0];
  const f32x2* emb = (const f32x2*)d_in[1];
  uint32_t B = (uint32_t)(in_sizes[0] / 3);

  size_t ws_lm   = (size_t)16 * B * sizeof(f32x2);          // 128 MiB at B=1M
  size_t ws_full = ws_lm + (size_t)3 * B * sizeof(float);   // + 12 MiB xyz

  if ((B % 256u) == 0u && ws_size >= ws_lm) {
    f32x2* ws = (f32x2*)d_ws;
    uint32_t gblocks = (B + 511u) / 512u;
    bool use_xyz = ws_size >= ws_full;
    if (use_xyz) {
      float* X = (float*)((char*)d_ws + ws_lm);
      float* Y = X + B;
      float* Z = Y + B;
      uint32_t pblocks = ((B >> 2) + 255u) / 256u;
      hipLaunchKernelGGL(prep_xyz_kernel, dim3(pblocks), dim3(256), 0, stream,
                         in, X, Y, Z, B);
      hipLaunchKernelGGL((gather_cm_kernel<true>), dim3(gblocks, 16), dim3(256),
                         0, stream, in, X, Y, Z, emb, ws, B);
    } else {
      hipLaunchKernelGGL((gather_cm_kernel<false>), dim3(gblocks, 16), dim3(256),
                         0, stream, in, nullptr, nullptr, nullptr, emb, ws, B);
    }
    uint32_t tblocks = B / 256u;
    hipLaunchKernelGGL(transpose_cm_kernel, dim3(tblocks), dim3(256), 0,
                       stream, ws, (f32x4*)d_out, B);
  } else {
    uint32_t pblocks = (B + 255u) / 256u;
    hipLaunchKernelGGL(grid_encode_fallback, dim3(pblocks), dim3(256), 0,
                       stream, in, emb, (f32x2*)d_out, B);
  }
}